// Round 1
// baseline (42.299 us; speedup 1.0000x reference)
//
#include <hip/hip_runtime.h>
#include <hip/hip_bf16.h>

// R3NN_20117626814733: the reference forward(dsl, embedded_samples, tree)
// is the identity on `tree` — the module body is `return tree`.
//
// Inputs (setup_inputs order):
//   d_in[0]: dsl               int64[128]            (unused)
//   d_in[1]: embedded_samples  f32[8,4096,512]       (unused)
//   d_in[2]: tree              f32[8,4096,1024]      -> copied to d_out
//
// out_size = 8*4096*1024 = 33,554,432 f32 elements (128 MiB).
// Pure memory-bound D2D copy; hipMemcpyAsync on the capture stream is
// graph-capturable and runs at near-peak HBM bandwidth.

extern "C" void kernel_launch(void* const* d_in, const int* in_sizes, int n_in,
                              void* d_out, int out_size, void* d_ws, size_t ws_size,
                              hipStream_t stream) {
    const float* tree = (const float*)d_in[2];
    float* out = (float*)d_out;
    const size_t nbytes = (size_t)out_size * sizeof(float);
    hipMemcpyAsync(out, tree, nbytes, hipMemcpyDeviceToDevice, stream);
}